// Round 5
// baseline (309.466 us; speedup 1.0000x reference)
//
#include <hip/hip_runtime.h>

#define Bsz 512
#define Nn  128
#define Dd  256
#define Tt  512

typedef __attribute__((ext_vector_type(8))) short short8;
typedef __attribute__((ext_vector_type(4))) float f32x4;

__device__ __forceinline__ ushort f2bf(float f) {
    union { float f; unsigned u; } v; v.f = f;
    unsigned r = v.u + 0x7fffu + ((v.u >> 16) & 1u);  // RNE
    return (ushort)(r >> 16);
}
__device__ __forceinline__ unsigned pk2(float a, float b) {
    return (unsigned)f2bf(a) | ((unsigned)f2bf(b) << 16);
}
__device__ __forceinline__ float bf2f(ushort u) {
    union { unsigned u; float f; } v; v.u = (unsigned)u << 16; return v.f;
}

// Relaxed barrier: drain LDS ops only; global loads/stores stay in flight
// (plain __syncthreads emits s_waitcnt vmcnt(0) and kills cross-phase
// prefetch -- the v3/v4 structural limit).
#define BARL() do { __builtin_amdgcn_sched_barrier(0); \
    asm volatile("s_waitcnt lgkmcnt(0)" ::: "memory"); \
    __builtin_amdgcn_s_barrier(); \
    __builtin_amdgcn_sched_barrier(0); } while (0)

// v5: 256 blocks x 1024 thr, 2 batches/block, ~148 KB LDS (1 block/CU,
// VGPR cap 128 so the 49-reg cross-batch prefetch does NOT spill like v3).
// Relaxed lgkm-only barriers keep prefetch loads + output stores in flight
// across the whole chain. Vectorized f32x4 gathers; halved dot-fold.
__global__ __launch_bounds__(1024, 4) void mega(
    const float* __restrict__ x, const float* __restrict__ adj,
    const int* __restrict__ head, const float* __restrict__ lin_w,
    const float* __restrict__ bias,
    float* __restrict__ emb, float* __restrict__ nadj)
{
    const int t = threadIdx.x;
    __shared__ __align__(16) ushort adjB[Nn][136];   // 34816 B (-> PT after G2)
    __shared__ __align__(16) ushort STl[Nn][136];    // 34816 B
    __shared__ __align__(16) uint   xT0[Nn][68];     // 34816 B  x bf16 pairs d 0..127
    __shared__ __align__(16) uint   xT1[Nn][68];     // 34816 B  d 128..255
    __shared__ __align__(16) float ttS[Nn], disS[Nn], alphaS[Nn], rowcS[Nn];
    __shared__ float maskS[Nn];
    __shared__ float partS[Nn][18];                  // dot partials (16 used)
    __shared__ int   flags[Nn];
    __shared__ int   nuniq;
    __shared__ float cutS;

    const float bias0 = bias[0];
    const int lane = t & 63, w = t >> 6;
    const int l15 = lane & 15, quad = lane >> 4;
    const int mrow  = (w & 7) * 16;
    const int nhalf = (w >> 3) * 64;
    const int r = t >> 3, seg = t & 7;
    const int xrow = t & 127, kq0 = t >> 7;          // kq0 in 0..7
    const float wv0 = lin_w[xrow], wv1 = lin_w[128 + xrow];

    // cross-batch prefetch holders (live only G2(it0) .. pack(it0 end))
    float pe0[8], pg0[8], pe1[8], pg1[8];
    float4 pav0, pav1, pav2, pav3;
    int hv1 = 0;

    for (int it = 0; it < 2; ++it) {
        const int b = 2 * blockIdx.x + it;

        if (t < Nn) flags[t] = 0;
        if (t == 0) { nuniq = 0; cutS = 0.f; }

        int hv = 0;
        float e0[8], g0[8], e1[8], g1[8];
        float4 a0v, a1v, a2v, a3v;
        if (it == 0) {
            if (t < Tt) hv = head[(size_t)b * Tt + t];
            const float* xb = x + (size_t)b * Nn * Dd + xrow;
#pragma unroll
            for (int k = 0; k < 8; ++k) e0[k] = xb[(size_t)(8 * kq0 + k) * Dd];
#pragma unroll
            for (int k = 0; k < 8; ++k) g0[k] = xb[(size_t)(64 + 8 * kq0 + k) * Dd];
#pragma unroll
            for (int k = 0; k < 8; ++k) e1[k] = xb[(size_t)(8 * kq0 + k) * Dd + 128];
#pragma unroll
            for (int k = 0; k < 8; ++k) g1[k] = xb[(size_t)(64 + 8 * kq0 + k) * Dd + 128];
            const float4* ab = (const float4*)(adj + (size_t)b * Nn * Nn);
            a0v = ab[t]; a1v = ab[t + 1024]; a2v = ab[t + 2048]; a3v = ab[t + 3072];
        } else {
            hv = hv1;
#pragma unroll
            for (int k = 0; k < 8; ++k) { e0[k] = pe0[k]; g0[k] = pg0[k]; e1[k] = pe1[k]; g1[k] = pg1[k]; }
            a0v = pav0; a1v = pav1; a2v = pav2; a3v = pav3;
        }

        // ---- dot partials (3-level fold; rest merged into row-sum phase) ----
#pragma unroll
        for (int k = 0; k < 8; ++k) {
            float re = e0[k] * wv0 + e1[k] * wv1;
            float rg = g0[k] * wv0 + g1[k] * wv1;
            re += __shfl_xor(re, 1); re += __shfl_xor(re, 2); re += __shfl_xor(re, 4);
            rg += __shfl_xor(rg, 1); rg += __shfl_xor(rg, 2); rg += __shfl_xor(rg, 4);
            if ((lane & 7) == 0) {
                int gc = (w & 1) * 8 + (lane >> 3);
                partS[8 * kq0 + k][gc]      = re;
                partS[64 + 8 * kq0 + k][gc] = rg;
            }
        }
        // ---- pack x -> xT0/xT1 ----
        {
            uint4 q;
            q.x = pk2(e0[0], e0[1]); q.y = pk2(e0[2], e0[3]);
            q.z = pk2(e0[4], e0[5]); q.w = pk2(e0[6], e0[7]);
            *(uint4*)&xT0[xrow][4 * kq0] = q;
            q.x = pk2(g0[0], g0[1]); q.y = pk2(g0[2], g0[3]);
            q.z = pk2(g0[4], g0[5]); q.w = pk2(g0[6], g0[7]);
            *(uint4*)&xT0[xrow][4 * kq0 + 32] = q;
            q.x = pk2(e1[0], e1[1]); q.y = pk2(e1[2], e1[3]);
            q.z = pk2(e1[4], e1[5]); q.w = pk2(e1[6], e1[7]);
            *(uint4*)&xT1[xrow][4 * kq0] = q;
            q.x = pk2(g1[0], g1[1]); q.y = pk2(g1[2], g1[3]);
            q.z = pk2(g1[4], g1[5]); q.w = pk2(g1[6], g1[7]);
            *(uint4*)&xT1[xrow][4 * kq0 + 32] = q;
        }
        // ---- pack adj -> adjB (bf16) ----
        {
            float4 v; int f, rr2, c; uint2 w2;
            v = a0v; f = t;        rr2 = f >> 5; c = (f & 31) * 4; w2.x = pk2(v.x, v.y); w2.y = pk2(v.z, v.w); *(uint2*)&adjB[rr2][c] = w2;
            v = a1v; f = t + 1024; rr2 = f >> 5; c = (f & 31) * 4; w2.x = pk2(v.x, v.y); w2.y = pk2(v.z, v.w); *(uint2*)&adjB[rr2][c] = w2;
            v = a2v; f = t + 2048; rr2 = f >> 5; c = (f & 31) * 4; w2.x = pk2(v.x, v.y); w2.y = pk2(v.z, v.w); *(uint2*)&adjB[rr2][c] = w2;
            v = a3v; f = t + 3072; rr2 = f >> 5; c = (f & 31) * 4; w2.x = pk2(v.x, v.y); w2.y = pk2(v.z, v.w); *(uint2*)&adjB[rr2][c] = w2;
        }
        BARL();                                            // B1

        if (t < Tt) flags[hv] = 1;

        {   // ---- row sums + dot reduce (8 lanes/row) ----
            short8 a0 = *(const short8*)&adjB[r][seg * 16];
            short8 a1 = *(const short8*)&adjB[r][seg * 16 + 8];
            float s = 0.f;
#pragma unroll
            for (int j = 0; j < 8; ++j) s += bf2f((ushort)a0[j]) + bf2f((ushort)a1[j]);
            float d = partS[r][2 * seg] + partS[r][2 * seg + 1];
            s += __shfl_xor(s, 1); s += __shfl_xor(s, 2); s += __shfl_xor(s, 4);
            d += __shfl_xor(d, 1); d += __shfl_xor(d, 2); d += __shfl_xor(d, 4);
            if (seg == 0) {
                maskS[r] = (s > 0.f) ? 1.f : 0.f;
                float dis = 1.f / sqrtf(fmaxf(s + 1.f, 1.f));
                disS[r] = dis;
                ttS[r]  = dis * d;
            }
        }
        BARL();                                            // B2

        {   // ---- matvec adj*tt -> alpha (f32x4 gathers) ----
            short8 a0 = *(const short8*)&adjB[r][seg * 16];
            short8 a1 = *(const short8*)&adjB[r][seg * 16 + 8];
            f32x4 t0 = *(const f32x4*)&ttS[seg * 16];
            f32x4 t1 = *(const f32x4*)&ttS[seg * 16 + 4];
            f32x4 t2 = *(const f32x4*)&ttS[seg * 16 + 8];
            f32x4 t3 = *(const f32x4*)&ttS[seg * 16 + 12];
            float s = 0.f;
#pragma unroll
            for (int j = 0; j < 4; ++j) {
                s += bf2f((ushort)a0[j])     * t0[j];
                s += bf2f((ushort)a0[4 + j]) * t1[j];
                s += bf2f((ushort)a1[j])     * t2[j];
                s += bf2f((ushort)a1[4 + j]) * t3[j];
            }
            s += __shfl_xor(s, 1); s += __shfl_xor(s, 2); s += __shfl_xor(s, 4);
            if (seg == 0) {
                float o = maskS[r] * disS[r] * (s + ttS[r]) + bias0;
                alphaS[r] = 1.f / (1.f + expf(-o * o));
                atomicAdd(&nuniq, flags[r]);
            }
        }
        BARL();                                            // B3

        {   // ---- k-th largest rank select (8 thr/row, vector gathers) ----
            int nu = nuniq;
            if (nu > 1) {
                float an = alphaS[r];
                int cg = 0, ce = 0;
#pragma unroll
                for (int v = 0; v < 4; ++v) {
                    f32x4 A = *(const f32x4*)&alphaS[seg * 16 + 4 * v];
#pragma unroll
                    for (int j = 0; j < 4; ++j) { cg += (A[j] > an); ce += (A[j] == an); }
                }
                cg += __shfl_xor(cg, 1); cg += __shfl_xor(cg, 2); cg += __shfl_xor(cg, 4);
                ce += __shfl_xor(ce, 1); ce += __shfl_xor(ce, 2); ce += __shfl_xor(ce, 4);
                if (seg == 0) {
                    int idx = (int)ceilf((float)nu * 0.1f);
                    if (idx > Nn - 1) idx = Nn - 1;
                    if (cg <= idx && idx < cg + ce) cutS = an;  // benign same-value race
                }
            }
        }
        BARL();                                            // B4

        {   // ---- matvec adj*u -> rowc; u inline from alpha/dis gathers ----
            const float cut = cutS;
            short8 a0 = *(const short8*)&adjB[r][seg * 16];
            short8 a1 = *(const short8*)&adjB[r][seg * 16 + 8];
            float s = 0.f;
#pragma unroll
            for (int v = 0; v < 4; ++v) {
                f32x4 A = *(const f32x4*)&alphaS[seg * 16 + 4 * v];
                f32x4 D = *(const f32x4*)&disS[seg * 16 + 4 * v];
#pragma unroll
                for (int j = 0; j < 4; ++j) {
                    float u = fmaxf(A[j] + 1e-7f - cut, 0.f) * D[j];
                    float av = (v < 2) ? bf2f((ushort)a0[4 * v + j])
                                       : bf2f((ushort)a1[4 * (v - 2) + j]);
                    s += av * u;
                }
            }
            s += __shfl_xor(s, 1); s += __shfl_xor(s, 2); s += __shfl_xor(s, 4);
            if (seg == 0) {
                float ur   = fmaxf(alphaS[r] + 1e-7f - cut, 0.f) * disS[r];
                float rsum = maskS[r] * disS[r] * (ur + s);
                rowcS[r]   = maskS[r] * disS[r] / fmaxf(rsum, 1e-12f);
            }
        }
        BARL();                                            // B5

        // ---- build ST[m][k] = rowc_k*(adj[k][m]+delta)*u_m (bf16) ----
        {
            const float cut = cutS;
            const int m = t & 127, sl = t >> 7, k0 = sl * 16;
            const float um = fmaxf(alphaS[m] + 1e-7f - cut, 0.f) * disS[m];
            f32x4 R0 = *(const f32x4*)&rowcS[k0];
            f32x4 R1 = *(const f32x4*)&rowcS[k0 + 4];
            f32x4 R2 = *(const f32x4*)&rowcS[k0 + 8];
            f32x4 R3 = *(const f32x4*)&rowcS[k0 + 12];
            float vv[16];
#pragma unroll
            for (int j = 0; j < 16; ++j) {
                int k = k0 + j;
                float rc = (j < 4) ? R0[j] : (j < 8) ? R1[j - 4] : (j < 12) ? R2[j - 8] : R3[j - 12];
                vv[j] = rc * (bf2f(adjB[k][m]) + ((k == m) ? 1.f : 0.f)) * um;
            }
            uint4 p0, p1;
            p0.x = pk2(vv[0],  vv[1]);  p0.y = pk2(vv[2],  vv[3]);
            p0.z = pk2(vv[4],  vv[5]);  p0.w = pk2(vv[6],  vv[7]);
            p1.x = pk2(vv[8],  vv[9]);  p1.y = pk2(vv[10], vv[11]);
            p1.z = pk2(vv[12], vv[13]); p1.w = pk2(vv[14], vv[15]);
            *(uint4*)&STl[m][k0]     = p0;
            *(uint4*)&STl[m][k0 + 8] = p1;
        }
        BARL();                                            // B6

        if (it == 0) {
            // ---- issue batch b+1 prefetch; flies across all BARLs below ----
            const float* xb = x + (size_t)(b + 1) * Nn * Dd + xrow;
#pragma unroll
            for (int k = 0; k < 8; ++k) pe0[k] = xb[(size_t)(8 * kq0 + k) * Dd];
#pragma unroll
            for (int k = 0; k < 8; ++k) pg0[k] = xb[(size_t)(64 + 8 * kq0 + k) * Dd];
#pragma unroll
            for (int k = 0; k < 8; ++k) pe1[k] = xb[(size_t)(8 * kq0 + k) * Dd + 128];
#pragma unroll
            for (int k = 0; k < 8; ++k) pg1[k] = xb[(size_t)(64 + 8 * kq0 + k) * Dd + 128];
            const float4* ab = (const float4*)(adj + (size_t)(b + 1) * Nn * Nn);
            pav0 = ab[t]; pav1 = ab[t + 1024]; pav2 = ab[t + 2048]; pav3 = ab[t + 3072];
            if (t < Tt) hv1 = head[(size_t)(b + 1) * Tt + t];
            __builtin_amdgcn_sched_barrier(0);  // pin load issue here
        }

        f32x4 acc[4];
        // ---- G2: P = adj * S ----
#pragma unroll
        for (int nt = 0; nt < 4; ++nt) acc[nt] = (f32x4){0.f, 0.f, 0.f, 0.f};
#pragma unroll
        for (int k0 = 0; k0 < 128; k0 += 32) {
            short8 a0 = *(const short8*)&adjB[mrow + l15][k0 + quad * 8];
#pragma unroll
            for (int nt = 0; nt < 4; ++nt) {
                short8 bf = *(const short8*)&STl[nhalf + nt * 16 + l15][k0 + quad * 8];
                acc[nt] = __builtin_amdgcn_mfma_f32_16x16x32_bf16(a0, bf, acc[nt], 0, 0, 0);
            }
        }
        BARL();                                            // B7: adj bf16 dead

        // ---- write P^T (bf16) into adjB region ----
        ushort (*PT)[136] = (ushort(*)[136])&adjB[0][0];
#pragma unroll
        for (int nt = 0; nt < 4; ++nt) {
            int j    = nhalf + nt * 16 + l15;
            int mcol = mrow + quad * 4;
            uint2 w2;
            w2.x = pk2(acc[nt][0], acc[nt][1]);
            w2.y = pk2(acc[nt][2], acc[nt][3]);
            *(uint2*)&PT[j][mcol] = w2;
        }
        BARL();                                            // B8

        // ---- G3: nadj = S^T P ----
#pragma unroll
        for (int nt = 0; nt < 4; ++nt) acc[nt] = (f32x4){0.f, 0.f, 0.f, 0.f};
#pragma unroll
        for (int k0 = 0; k0 < 128; k0 += 32) {
            short8 a0 = *(const short8*)&STl[mrow + l15][k0 + quad * 8];
#pragma unroll
            for (int nt = 0; nt < 4; ++nt) {
                short8 bf = *(const short8*)&PT[nhalf + nt * 16 + l15][k0 + quad * 8];
                acc[nt] = __builtin_amdgcn_mfma_f32_16x16x32_bf16(a0, bf, acc[nt], 0, 0, 0);
            }
        }
#pragma unroll
        for (int nt = 0; nt < 4; ++nt)
#pragma unroll
            for (int rr2 = 0; rr2 < 4; ++rr2) {
                int row = mrow + quad * 4 + rr2;
                int col = nhalf + nt * 16 + l15;
                nadj[((size_t)b * Nn + row) * Nn + col] = acc[nt][rr2];
            }

        // ---- emb = S^T x from dedicated xT0/xT1 (no barriers needed) ----
        const int dcb = (w >> 3) * 64;
        f32x4 accE[4];
#pragma unroll
        for (int nt = 0; nt < 4; ++nt) accE[nt] = (f32x4){0.f, 0.f, 0.f, 0.f};
#pragma unroll
        for (int ks = 0; ks < 4; ++ks) {
            short8 aE = *(const short8*)&STl[mrow + l15][ks * 32 + quad * 8];
#pragma unroll
            for (int nt = 0; nt < 4; ++nt) {
                short8 bf = *(const short8*)&xT0[dcb + nt * 16 + l15][ks * 16 + quad * 4];
                accE[nt] = __builtin_amdgcn_mfma_f32_16x16x32_bf16(aE, bf, accE[nt], 0, 0, 0);
            }
        }
#pragma unroll
        for (int nt = 0; nt < 4; ++nt)
#pragma unroll
            for (int rr2 = 0; rr2 < 4; ++rr2) {
                int row = mrow + quad * 4 + rr2;
                int col = dcb + nt * 16 + l15;
                emb[((size_t)b * Nn + row) * Dd + col] = accE[nt][rr2];
            }

#pragma unroll
        for (int nt = 0; nt < 4; ++nt) accE[nt] = (f32x4){0.f, 0.f, 0.f, 0.f};
#pragma unroll
        for (int ks = 0; ks < 4; ++ks) {
            short8 aE = *(const short8*)&STl[mrow + l15][ks * 32 + quad * 8];
#pragma unroll
            for (int nt = 0; nt < 4; ++nt) {
                short8 bf = *(const short8*)&xT1[dcb + nt * 16 + l15][ks * 16 + quad * 4];
                accE[nt] = __builtin_amdgcn_mfma_f32_16x16x32_bf16(aE, bf, accE[nt], 0, 0, 0);
            }
        }
#pragma unroll
        for (int nt = 0; nt < 4; ++nt)
#pragma unroll
            for (int rr2 = 0; rr2 < 4; ++rr2) {
                int row = mrow + quad * 4 + rr2;
                int col = 128 + dcb + nt * 16 + l15;
                emb[((size_t)b * Nn + row) * Dd + col] = accE[nt][rr2];
            }

        BARL();   // B9: all LDS reads done -> next iteration may overwrite
    }
}

extern "C" void kernel_launch(void* const* d_in, const int* in_sizes, int n_in,
                              void* d_out, int out_size, void* d_ws, size_t ws_size,
                              hipStream_t stream)
{
    const float* x     = (const float*)d_in[0];
    const float* adj   = (const float*)d_in[1];
    const int*   head  = (const int*)d_in[2];
    const float* lin_w = (const float*)d_in[3];
    const float* bias  = (const float*)d_in[4];

    float* emb  = (float*)d_out;                 // [B,N,D]
    float* nadj = emb + (size_t)Bsz * Nn * Dd;   // [B,N,N]

    mega<<<Bsz / 2, 1024, 0, stream>>>(x, adj, head, lin_w, bias, emb, nadj);
}

// Round 6
// 204.922 us; speedup vs baseline: 1.5102x; 1.5102x over previous
//
#include <hip/hip_runtime.h>

#define Bsz 512
#define Nn  128
#define Dd  256
#define Tt  512

typedef __attribute__((ext_vector_type(8))) short short8;
typedef __attribute__((ext_vector_type(4))) float f32x4;

__device__ __forceinline__ ushort f2bf(float f) {
    union { float f; unsigned u; } v; v.f = f;
    unsigned r = v.u + 0x7fffu + ((v.u >> 16) & 1u);  // RNE
    return (ushort)(r >> 16);
}
__device__ __forceinline__ unsigned pk2(float a, float b) {
    return (unsigned)f2bf(a) | ((unsigned)f2bf(b) << 16);
}
__device__ __forceinline__ float bf2f(ushort u) {
    union { unsigned u; float f; } v; v.u = (unsigned)u << 16; return v.f;
}

// ---- LDS swizzle: granule(16B)' = g ^ S(row); S mixes row&7 AND row>>3 so
// rows 8 apart (which alias banks exactly at any 16B-multiple stride) are
// also spread. Applied to EVERY access of adjB/STl/PT/xT (both-sides rule).
__device__ __forceinline__ int SWZ(int row, int g) {
    return g ^ ((row ^ (row >> 3)) & 7);
}
// adj-style arrays: 128 rows x 136 ushorts (272 B, 17 granules; g16 = pad)
__device__ __forceinline__ ushort* AP(ushort* base, int row, int col) {
    return base + row * 136 + (SWZ(row, col >> 3) << 3) + (col & 7);
}
// xT arrays: 128 rows x 68 uints (272 B); col in uints
__device__ __forceinline__ uint* XP(uint* base, int row, int col) {
    return base + row * 68 + (SWZ(row, col >> 2) << 2) + (col & 3);
}

// v6: v4 base (512 blocks, 1 batch/block, no cross-batch reg prefetch --
// v3/v5 proved hipcc spills it) + bank-conflict-free swizzled LDS +
// f32 row-sums folded into staging (one less heavy phase, better precision).
__global__ __launch_bounds__(1024, 4) void mega(
    const float* __restrict__ x, const float* __restrict__ adj,
    const int* __restrict__ head, const float* __restrict__ lin_w,
    const float* __restrict__ bias,
    float* __restrict__ emb, float* __restrict__ nadj)
{
    const int t = threadIdx.x, b = blockIdx.x;
    __shared__ __align__(16) ushort adjR[Nn * 136];   // 34816 B (-> PT after G2)
    __shared__ __align__(16) ushort stR[Nn * 136];    // 34816 B
    __shared__ __align__(16) uint   xtR0[Nn * 68];    // 34816 B  x bf16 pairs d 0..127
    __shared__ __align__(16) uint   xtR1[Nn * 68];    // 34816 B  d 128..255
    __shared__ float ttS[Nn], disS[Nn], maskS[Nn], alphaS[Nn], rowcS[Nn];
    __shared__ float partS[Nn][18];                   // dot partials (16 used)
    __shared__ float partS2[Nn][4];                   // row-sum partials
    __shared__ int   flags[Nn];
    __shared__ int   nuniq;
    __shared__ float cutS;

    const float bias0 = bias[0];
    if (t < Nn) flags[t] = 0;
    if (t == 0) { nuniq = 0; cutS = 0.f; }

    const int lane = t & 63, w = t >> 6;
    const int l15 = lane & 15, quad = lane >> 4;
    const int mrow  = (w & 7) * 16;
    const int nhalf = (w >> 3) * 64;
    const int r = t >> 3, seg = t & 7;
    const int xrow = t & 127, kq0 = t >> 7;          // kq0 in 0..7
    const float wv0 = lin_w[xrow], wv1 = lin_w[128 + xrow];

    int hv = 0;
    if (t < Tt) hv = head[(size_t)b * Tt + t];

    // ================= read burst: x (once) + adj, overlapped ==============
    float e0[8], g0[8], e1[8], g1[8];
    {
        const float* xb = x + (size_t)b * Nn * Dd + xrow;
#pragma unroll
        for (int k = 0; k < 8; ++k) e0[k] = xb[(size_t)(8 * kq0 + k) * Dd];
#pragma unroll
        for (int k = 0; k < 8; ++k) g0[k] = xb[(size_t)(64 + 8 * kq0 + k) * Dd];
#pragma unroll
        for (int k = 0; k < 8; ++k) e1[k] = xb[(size_t)(8 * kq0 + k) * Dd + 128];
#pragma unroll
        for (int k = 0; k < 8; ++k) g1[k] = xb[(size_t)(64 + 8 * kq0 + k) * Dd + 128];
    }
    float4 av0, av1, av2, av3;
    {
        const float4* adjb = (const float4*)(adj + (size_t)b * Nn * Nn);
        av0 = adjb[t]; av1 = adjb[t + 1024]; av2 = adjb[t + 2048]; av3 = adjb[t + 3072];
    }

    // ---- dot partials: 3-level fold -> partS[node][16 groups] ----
#pragma unroll
    for (int k = 0; k < 8; ++k) {
        float re = e0[k] * wv0 + e1[k] * wv1;
        float rg = g0[k] * wv0 + g1[k] * wv1;
        re += __shfl_xor(re, 1); re += __shfl_xor(re, 2); re += __shfl_xor(re, 4);
        rg += __shfl_xor(rg, 1); rg += __shfl_xor(rg, 2); rg += __shfl_xor(rg, 4);
        if ((lane & 7) == 0) {
            int gc = (w & 1) * 8 + (lane >> 3);
            partS[8 * kq0 + k][gc]      = re;
            partS[64 + 8 * kq0 + k][gc] = rg;
        }
    }

    // ---- f32 row sums folded into staging: 3-level fold -> partS2[row][4] ----
    {
        float s0 = av0.x + av0.y + av0.z + av0.w;
        float s1 = av1.x + av1.y + av1.z + av1.w;
        float s2 = av2.x + av2.y + av2.z + av2.w;
        float s3 = av3.x + av3.y + av3.z + av3.w;
        s0 += __shfl_xor(s0, 1); s0 += __shfl_xor(s0, 2); s0 += __shfl_xor(s0, 4);
        s1 += __shfl_xor(s1, 1); s1 += __shfl_xor(s1, 2); s1 += __shfl_xor(s1, 4);
        s2 += __shfl_xor(s2, 1); s2 += __shfl_xor(s2, 2); s2 += __shfl_xor(s2, 4);
        s3 += __shfl_xor(s3, 1); s3 += __shfl_xor(s3, 2); s3 += __shfl_xor(s3, 4);
        if ((lane & 7) == 0) {
            int q = (lane & 31) >> 3;        // 8-lane subgroup within the 32-thread row group
            int row0 = t >> 5;
            partS2[row0][q]       = s0;
            partS2[row0 + 32][q]  = s1;
            partS2[row0 + 64][q]  = s2;
            partS2[row0 + 96][q]  = s3;
        }
    }

    // ---- pack x -> xT0/xT1 (swizzled granules) ----
    {
        uint4 q;
        q.x = pk2(e0[0], e0[1]); q.y = pk2(e0[2], e0[3]);
        q.z = pk2(e0[4], e0[5]); q.w = pk2(e0[6], e0[7]);
        *(uint4*)XP(xtR0, xrow, 4 * kq0) = q;
        q.x = pk2(g0[0], g0[1]); q.y = pk2(g0[2], g0[3]);
        q.z = pk2(g0[4], g0[5]); q.w = pk2(g0[6], g0[7]);
        *(uint4*)XP(xtR0, xrow, 4 * kq0 + 32) = q;
        q.x = pk2(e1[0], e1[1]); q.y = pk2(e1[2], e1[3]);
        q.z = pk2(e1[4], e1[5]); q.w = pk2(e1[6], e1[7]);
        *(uint4*)XP(xtR1, xrow, 4 * kq0) = q;
        q.x = pk2(g1[0], g1[1]); q.y = pk2(g1[2], g1[3]);
        q.z = pk2(g1[4], g1[5]); q.w = pk2(g1[6], g1[7]);
        *(uint4*)XP(xtR1, xrow, 4 * kq0 + 32) = q;
    }
    // ---- pack adj -> adjB (bf16, swizzled) ----
    {
        float4 v; int f, rr2, c; uint2 w2;
        v = av0; f = t;        rr2 = f >> 5; c = (f & 31) * 4; w2.x = pk2(v.x, v.y); w2.y = pk2(v.z, v.w); *(uint2*)AP(adjR, rr2, c) = w2;
        v = av1; f = t + 1024; rr2 = f >> 5; c = (f & 31) * 4; w2.x = pk2(v.x, v.y); w2.y = pk2(v.z, v.w); *(uint2*)AP(adjR, rr2, c) = w2;
        v = av2; f = t + 2048; rr2 = f >> 5; c = (f & 31) * 4; w2.x = pk2(v.x, v.y); w2.y = pk2(v.z, v.w); *(uint2*)AP(adjR, rr2, c) = w2;
        v = av3; f = t + 3072; rr2 = f >> 5; c = (f & 31) * 4; w2.x = pk2(v.x, v.y); w2.y = pk2(v.z, v.w); *(uint2*)AP(adjR, rr2, c) = w2;
    }
    __syncthreads();                                           // B1

    if (t < Tt) flags[hv] = 1;

    {   // ---- combine dot + row-sum partials (8 lanes/row) ----
        float d = partS[r][2 * seg] + partS[r][2 * seg + 1];
        float s = (seg < 4) ? partS2[r][seg] : 0.f;
        d += __shfl_xor(d, 1); d += __shfl_xor(d, 2); d += __shfl_xor(d, 4);
        s += __shfl_xor(s, 1); s += __shfl_xor(s, 2); s += __shfl_xor(s, 4);
        if (seg == 0) {
            maskS[r] = (s > 0.f) ? 1.f : 0.f;
            float dis = 1.f / sqrtf(fmaxf(s + 1.f, 1.f));
            disS[r] = dis;
            ttS[r]  = dis * d;
        }
    }
    __syncthreads();                                           // B2

    {   // ---- matvec adj*tt -> alpha ----
        short8 a0 = *(const short8*)AP(adjR, r, seg * 16);
        short8 a1 = *(const short8*)AP(adjR, r, seg * 16 + 8);
        f32x4 t0 = *(const f32x4*)&ttS[seg * 16];
        f32x4 t1 = *(const f32x4*)&ttS[seg * 16 + 4];
        f32x4 t2 = *(const f32x4*)&ttS[seg * 16 + 8];
        f32x4 t3 = *(const f32x4*)&ttS[seg * 16 + 12];
        float s = 0.f;
#pragma unroll
        for (int j = 0; j < 4; ++j) {
            s += bf2f((ushort)a0[j])     * t0[j];
            s += bf2f((ushort)a0[4 + j]) * t1[j];
            s += bf2f((ushort)a1[j])     * t2[j];
            s += bf2f((ushort)a1[4 + j]) * t3[j];
        }
        s += __shfl_xor(s, 1); s += __shfl_xor(s, 2); s += __shfl_xor(s, 4);
        if (seg == 0) {
            float o = maskS[r] * disS[r] * (s + ttS[r]) + bias0;
            alphaS[r] = 1.f / (1.f + expf(-o * o));
            atomicAdd(&nuniq, flags[r]);
        }
    }
    __syncthreads();                                           // B3

    {   // ---- k-th largest rank select (8 thr/row, vector gathers) ----
        int nu = nuniq;
        if (nu > 1) {
            float an = alphaS[r];
            int cg = 0, ce = 0;
#pragma unroll
            for (int v = 0; v < 4; ++v) {
                f32x4 A = *(const f32x4*)&alphaS[seg * 16 + 4 * v];
#pragma unroll
                for (int j = 0; j < 4; ++j) { cg += (A[j] > an); ce += (A[j] == an); }
            }
            cg += __shfl_xor(cg, 1); cg += __shfl_xor(cg, 2); cg += __shfl_xor(cg, 4);
            ce += __shfl_xor(ce, 1); ce += __shfl_xor(ce, 2); ce += __shfl_xor(ce, 4);
            if (seg == 0) {
                int idx = (int)ceilf((float)nu * 0.1f);
                if (idx > Nn - 1) idx = Nn - 1;
                if (cg <= idx && idx < cg + ce) cutS = an;  // benign same-value race
            }
        }
    }
    __syncthreads();                                           // B4

    {   // ---- matvec adj*u -> rowc; u inline from alpha/dis ----
        const float cut = cutS;
        short8 a0 = *(const short8*)AP(adjR, r, seg * 16);
        short8 a1 = *(const short8*)AP(adjR, r, seg * 16 + 8);
        float s = 0.f;
#pragma unroll
        for (int v = 0; v < 4; ++v) {
            f32x4 A = *(const f32x4*)&alphaS[seg * 16 + 4 * v];
            f32x4 D = *(const f32x4*)&disS[seg * 16 + 4 * v];
#pragma unroll
            for (int j = 0; j < 4; ++j) {
                float u = fmaxf(A[j] + 1e-7f - cut, 0.f) * D[j];
                float av = (v < 2) ? bf2f((ushort)a0[4 * v + j])
                                   : bf2f((ushort)a1[4 * (v - 2) + j]);
                s += av * u;
            }
        }
        s += __shfl_xor(s, 1); s += __shfl_xor(s, 2); s += __shfl_xor(s, 4);
        if (seg == 0) {
            float ur   = fmaxf(alphaS[r] + 1e-7f - cut, 0.f) * disS[r];
            float rsum = maskS[r] * disS[r] * (ur + s);
            rowcS[r]   = maskS[r] * disS[r] / fmaxf(rsum, 1e-12f);
        }
    }
    __syncthreads();                                           // B5

    // ---- build ST[m][k] = rowc_k*(adj[k][m]+delta)*u_m (bf16, swizzled) ----
    {
        const float cut = cutS;
        const int m = t & 127, sl = t >> 7, k0 = sl * 16;
        const float um = fmaxf(alphaS[m] + 1e-7f - cut, 0.f) * disS[m];
        float vv[16];
#pragma unroll
        for (int j = 0; j < 16; ++j) {
            int k = k0 + j;
            vv[j] = rowcS[k] * (bf2f(*AP(adjR, k, m)) + ((k == m) ? 1.f : 0.f)) * um;
        }
        uint4 p0, p1;
        p0.x = pk2(vv[0],  vv[1]);  p0.y = pk2(vv[2],  vv[3]);
        p0.z = pk2(vv[4],  vv[5]);  p0.w = pk2(vv[6],  vv[7]);
        p1.x = pk2(vv[8],  vv[9]);  p1.y = pk2(vv[10], vv[11]);
        p1.z = pk2(vv[12], vv[13]); p1.w = pk2(vv[14], vv[15]);
        *(uint4*)AP(stR, m, k0)     = p0;
        *(uint4*)AP(stR, m, k0 + 8) = p1;
    }
    __syncthreads();                                           // B6

    f32x4 acc[4];
    // ---- G2: P = adj * S ----
#pragma unroll
    for (int nt = 0; nt < 4; ++nt) acc[nt] = (f32x4){0.f, 0.f, 0.f, 0.f};
#pragma unroll
    for (int k0 = 0; k0 < 128; k0 += 32) {
        short8 a0 = *(const short8*)AP(adjR, mrow + l15, k0 + quad * 8);
#pragma unroll
        for (int nt = 0; nt < 4; ++nt) {
            short8 bf = *(const short8*)AP(stR, nhalf + nt * 16 + l15, k0 + quad * 8);
            acc[nt] = __builtin_amdgcn_mfma_f32_16x16x32_bf16(a0, bf, acc[nt], 0, 0, 0);
        }
    }
    __syncthreads();                                           // B7: adj bf16 dead

    // ---- write P^T (bf16) into adjB region (same swizzle) ----
#pragma unroll
    for (int nt = 0; nt < 4; ++nt) {
        int j    = nhalf + nt * 16 + l15;
        int mcol = mrow + quad * 4;
        uint2 w2;
        w2.x = pk2(acc[nt][0], acc[nt][1]);
        w2.y = pk2(acc[nt][2], acc[nt][3]);
        *(uint2*)AP(adjR, j, mcol) = w2;
    }
    __syncthreads();                                           // B8

    // ---- G3: nadj = S^T P ----
#pragma unroll
    for (int nt = 0; nt < 4; ++nt) acc[nt] = (f32x4){0.f, 0.f, 0.f, 0.f};
#pragma unroll
    for (int k0 = 0; k0 < 128; k0 += 32) {
        short8 a0 = *(const short8*)AP(stR, mrow + l15, k0 + quad * 8);
#pragma unroll
        for (int nt = 0; nt < 4; ++nt) {
            short8 bf = *(const short8*)AP(adjR, nhalf + nt * 16 + l15, k0 + quad * 8);
            acc[nt] = __builtin_amdgcn_mfma_f32_16x16x32_bf16(a0, bf, acc[nt], 0, 0, 0);
        }
    }
#pragma unroll
    for (int nt = 0; nt < 4; ++nt)
#pragma unroll
        for (int rr2 = 0; rr2 < 4; ++rr2) {
            int row = mrow + quad * 4 + rr2;
            int col = nhalf + nt * 16 + l15;
            nadj[((size_t)b * Nn + row) * Nn + col] = acc[nt][rr2];
        }

    // ---- emb = S^T x from xT0/xT1 (no further barriers) ----
    const int dcb = (w >> 3) * 64;
    f32x4 accE[4];
#pragma unroll
    for (int nt = 0; nt < 4; ++nt) accE[nt] = (f32x4){0.f, 0.f, 0.f, 0.f};
#pragma unroll
    for (int ks = 0; ks < 4; ++ks) {
        short8 aE = *(const short8*)AP(stR, mrow + l15, ks * 32 + quad * 8);
#pragma unroll
        for (int nt = 0; nt < 4; ++nt) {
            short8 bf = *(const short8*)XP(xtR0, dcb + nt * 16 + l15, ks * 16 + quad * 4);
            accE[nt] = __builtin_amdgcn_mfma_f32_16x16x32_bf16(aE, bf, accE[nt], 0, 0, 0);
        }
    }
#pragma unroll
    for (int nt = 0; nt < 4; ++nt)
#pragma unroll
        for (int rr2 = 0; rr2 < 4; ++rr2) {
            int row = mrow + quad * 4 + rr2;
            int col = dcb + nt * 16 + l15;
            emb[((size_t)b * Nn + row) * Dd + col] = accE[nt][rr2];
        }

#pragma unroll
    for (int nt = 0; nt < 4; ++nt) accE[nt] = (f32x4){0.f, 0.f, 0.f, 0.f};
#pragma unroll
    for (int ks = 0; ks < 4; ++ks) {
        short8 aE = *(const short8*)AP(stR, mrow + l15, ks * 32 + quad * 8);
#pragma unroll
        for (int nt = 0; nt < 4; ++nt) {
            short8 bf = *(const short8*)XP(xtR1, dcb + nt * 16 + l15, ks * 16 + quad * 4);
            accE[nt] = __builtin_amdgcn_mfma_f32_16x16x32_bf16(aE, bf, accE[nt], 0, 0, 0);
        }
    }
#pragma unroll
    for (int nt = 0; nt < 4; ++nt)
#pragma unroll
        for (int rr2 = 0; rr2 < 4; ++rr2) {
            int row = mrow + quad * 4 + rr2;
            int col = 128 + dcb + nt * 16 + l15;
            emb[((size_t)b * Nn + row) * Dd + col] = accE[nt][rr2];
        }
}

extern "C" void kernel_launch(void* const* d_in, const int* in_sizes, int n_in,
                              void* d_out, int out_size, void* d_ws, size_t ws_size,
                              hipStream_t stream)
{
    const float* x     = (const float*)d_in[0];
    const float* adj   = (const float*)d_in[1];
    const int*   head  = (const int*)d_in[2];
    const float* lin_w = (const float*)d_in[3];
    const float* bias  = (const float*)d_in[4];

    float* emb  = (float*)d_out;                 // [B,N,D]
    float* nadj = emb + (size_t)Bsz * Nn * Dd;   // [B,N,N]

    mega<<<Bsz, 1024, 0, stream>>>(x, adj, head, lin_w, bias, emb, nadj);
}

// Round 7
// 201.143 us; speedup vs baseline: 1.5385x; 1.0188x over previous
//
#include <hip/hip_runtime.h>

#define Bsz 512
#define Nn  128
#define Dd  256
#define Tt  512

typedef __attribute__((ext_vector_type(8))) short short8;
typedef __attribute__((ext_vector_type(4))) float f32x4;

__device__ __forceinline__ ushort f2bf(float f) {
    union { float f; unsigned u; } v; v.f = f;
    unsigned r = v.u + 0x7fffu + ((v.u >> 16) & 1u);  // RNE
    return (ushort)(r >> 16);
}
__device__ __forceinline__ unsigned pk2(float a, float b) {
    return (unsigned)f2bf(a) | ((unsigned)f2bf(b) << 16);
}
__device__ __forceinline__ float bf2f(ushort u) {
    union { unsigned u; float f; } v; v.u = (unsigned)u << 16; return v.f;
}

// ---- LDS swizzle, v7: rows are EXACTLY 256 B so row start ≡ bank 0 and
// bank-group is determined by the 16-B granule alone. Then the involution
// g' = g ^ (row&7) is a clean per-row permutation of the 8 bank-groups.
// (v6 bug: 272-B rows add 4*row mod 32 banks; XOR algebra collapses ->
// 4-way conflicts. XOR swizzles REQUIRE row stride ≡ 0 mod 128 B.)
// Applied via these helpers to EVERY access (both-sides-or-neither).
__device__ __forceinline__ ushort* AP(ushort* base, int row, int col) {
    // 128-ushort rows; col in ushorts
    return base + row * 128 + (((col >> 3) ^ (row & 7)) << 3) + (col & 7);
}
__device__ __forceinline__ uint* XP(uint* base, int row, int col) {
    // 64-uint rows; col in uints
    return base + row * 64 + (((col >> 2) ^ (row & 7)) << 2) + (col & 3);
}

// v7: v4 base (512 blocks, 1 batch/block; no cross-batch reg prefetch --
// v3/v5 proved hipcc spills it) + CORRECT 256B-row XOR swizzle everywhere
// + v6's f32 row-sum fold (one less adjB-read phase).
__global__ __launch_bounds__(1024, 4) void mega(
    const float* __restrict__ x, const float* __restrict__ adj,
    const int* __restrict__ head, const float* __restrict__ lin_w,
    const float* __restrict__ bias,
    float* __restrict__ emb, float* __restrict__ nadj)
{
    const int t = threadIdx.x, b = blockIdx.x;
    __shared__ __align__(16) ushort adjR[Nn * 128];   // 32768 B (-> PT after G2)
    __shared__ __align__(16) ushort stR[Nn * 128];    // 32768 B
    __shared__ __align__(16) uint   xtR0[Nn * 64];    // 32768 B  x bf16 pairs d 0..127
    __shared__ __align__(16) uint   xtR1[Nn * 64];    // 32768 B  d 128..255
    __shared__ float ttS[Nn], disS[Nn], maskS[Nn], alphaS[Nn], rowcS[Nn];
    __shared__ float partS[Nn][18];                   // dot partials (16 used)
    __shared__ float partS2[Nn][4];                   // row-sum partials
    __shared__ int   flags[Nn];
    __shared__ int   nuniq;
    __shared__ float cutS;

    const float bias0 = bias[0];
    if (t < Nn) flags[t] = 0;
    if (t == 0) { nuniq = 0; cutS = 0.f; }

    const int lane = t & 63, w = t >> 6;
    const int l15 = lane & 15, quad = lane >> 4;
    const int mrow  = (w & 7) * 16;
    const int nhalf = (w >> 3) * 64;
    const int r = t >> 3, seg = t & 7;
    const int xrow = t & 127, kq0 = t >> 7;          // kq0 in 0..7
    const float wv0 = lin_w[xrow], wv1 = lin_w[128 + xrow];

    int hv = 0;
    if (t < Tt) hv = head[(size_t)b * Tt + t];

    // ================= read burst: x (once) + adj, overlapped ==============
    float e0[8], g0[8], e1[8], g1[8];
    {
        const float* xb = x + (size_t)b * Nn * Dd + xrow;
#pragma unroll
        for (int k = 0; k < 8; ++k) e0[k] = xb[(size_t)(8 * kq0 + k) * Dd];
#pragma unroll
        for (int k = 0; k < 8; ++k) g0[k] = xb[(size_t)(64 + 8 * kq0 + k) * Dd];
#pragma unroll
        for (int k = 0; k < 8; ++k) e1[k] = xb[(size_t)(8 * kq0 + k) * Dd + 128];
#pragma unroll
        for (int k = 0; k < 8; ++k) g1[k] = xb[(size_t)(64 + 8 * kq0 + k) * Dd + 128];
    }
    float4 av0, av1, av2, av3;
    {
        const float4* adjb = (const float4*)(adj + (size_t)b * Nn * Nn);
        av0 = adjb[t]; av1 = adjb[t + 1024]; av2 = adjb[t + 2048]; av3 = adjb[t + 3072];
    }

    // ---- dot partials: 3-level fold -> partS[node][16 groups] ----
#pragma unroll
    for (int k = 0; k < 8; ++k) {
        float re = e0[k] * wv0 + e1[k] * wv1;
        float rg = g0[k] * wv0 + g1[k] * wv1;
        re += __shfl_xor(re, 1); re += __shfl_xor(re, 2); re += __shfl_xor(re, 4);
        rg += __shfl_xor(rg, 1); rg += __shfl_xor(rg, 2); rg += __shfl_xor(rg, 4);
        if ((lane & 7) == 0) {
            int gc = (w & 1) * 8 + (lane >> 3);
            partS[8 * kq0 + k][gc]      = re;
            partS[64 + 8 * kq0 + k][gc] = rg;
        }
    }

    // ---- f32 row sums folded into staging -> partS2[row][4] ----
    {
        float s0 = av0.x + av0.y + av0.z + av0.w;
        float s1 = av1.x + av1.y + av1.z + av1.w;
        float s2 = av2.x + av2.y + av2.z + av2.w;
        float s3 = av3.x + av3.y + av3.z + av3.w;
        s0 += __shfl_xor(s0, 1); s0 += __shfl_xor(s0, 2); s0 += __shfl_xor(s0, 4);
        s1 += __shfl_xor(s1, 1); s1 += __shfl_xor(s1, 2); s1 += __shfl_xor(s1, 4);
        s2 += __shfl_xor(s2, 1); s2 += __shfl_xor(s2, 2); s2 += __shfl_xor(s2, 4);
        s3 += __shfl_xor(s3, 1); s3 += __shfl_xor(s3, 2); s3 += __shfl_xor(s3, 4);
        if ((lane & 7) == 0) {
            int q = (lane & 31) >> 3;
            int row0 = t >> 5;
            partS2[row0][q]       = s0;
            partS2[row0 + 32][q]  = s1;
            partS2[row0 + 64][q]  = s2;
            partS2[row0 + 96][q]  = s3;
        }
    }

    // ---- pack x -> xT0/xT1 (swizzled granules) ----
    {
        uint4 q;
        q.x = pk2(e0[0], e0[1]); q.y = pk2(e0[2], e0[3]);
        q.z = pk2(e0[4], e0[5]); q.w = pk2(e0[6], e0[7]);
        *(uint4*)XP(xtR0, xrow, 4 * kq0) = q;
        q.x = pk2(g0[0], g0[1]); q.y = pk2(g0[2], g0[3]);
        q.z = pk2(g0[4], g0[5]); q.w = pk2(g0[6], g0[7]);
        *(uint4*)XP(xtR0, xrow, 4 * kq0 + 32) = q;
        q.x = pk2(e1[0], e1[1]); q.y = pk2(e1[2], e1[3]);
        q.z = pk2(e1[4], e1[5]); q.w = pk2(e1[6], e1[7]);
        *(uint4*)XP(xtR1, xrow, 4 * kq0) = q;
        q.x = pk2(g1[0], g1[1]); q.y = pk2(g1[2], g1[3]);
        q.z = pk2(g1[4], g1[5]); q.w = pk2(g1[6], g1[7]);
        *(uint4*)XP(xtR1, xrow, 4 * kq0 + 32) = q;
    }
    // ---- pack adj -> adjR (bf16, swizzled) ----
    {
        float4 v; int f, rr2, c; uint2 w2;
        v = av0; f = t;        rr2 = f >> 5; c = (f & 31) * 4; w2.x = pk2(v.x, v.y); w2.y = pk2(v.z, v.w); *(uint2*)AP(adjR, rr2, c) = w2;
        v = av1; f = t + 1024; rr2 = f >> 5; c = (f & 31) * 4; w2.x = pk2(v.x, v.y); w2.y = pk2(v.z, v.w); *(uint2*)AP(adjR, rr2, c) = w2;
        v = av2; f = t + 2048; rr2 = f >> 5; c = (f & 31) * 4; w2.x = pk2(v.x, v.y); w2.y = pk2(v.z, v.w); *(uint2*)AP(adjR, rr2, c) = w2;
        v = av3; f = t + 3072; rr2 = f >> 5; c = (f & 31) * 4; w2.x = pk2(v.x, v.y); w2.y = pk2(v.z, v.w); *(uint2*)AP(adjR, rr2, c) = w2;
    }
    __syncthreads();                                           // B1

    if (t < Tt) flags[hv] = 1;

    {   // ---- combine dot + row-sum partials (8 lanes/row) ----
        float d = partS[r][2 * seg] + partS[r][2 * seg + 1];
        float s = (seg < 4) ? partS2[r][seg] : 0.f;
        d += __shfl_xor(d, 1); d += __shfl_xor(d, 2); d += __shfl_xor(d, 4);
        s += __shfl_xor(s, 1); s += __shfl_xor(s, 2); s += __shfl_xor(s, 4);
        if (seg == 0) {
            maskS[r] = (s > 0.f) ? 1.f : 0.f;
            float dis = 1.f / sqrtf(fmaxf(s + 1.f, 1.f));
            disS[r] = dis;
            ttS[r]  = dis * d;
        }
    }
    __syncthreads();                                           // B2

    {   // ---- matvec adj*tt -> alpha ----
        short8 a0 = *(const short8*)AP(adjR, r, seg * 16);
        short8 a1 = *(const short8*)AP(adjR, r, seg * 16 + 8);
        f32x4 t0 = *(const f32x4*)&ttS[seg * 16];
        f32x4 t1 = *(const f32x4*)&ttS[seg * 16 + 4];
        f32x4 t2 = *(const f32x4*)&ttS[seg * 16 + 8];
        f32x4 t3 = *(const f32x4*)&ttS[seg * 16 + 12];
        float s = 0.f;
#pragma unroll
        for (int j = 0; j < 4; ++j) {
            s += bf2f((ushort)a0[j])     * t0[j];
            s += bf2f((ushort)a0[4 + j]) * t1[j];
            s += bf2f((ushort)a1[j])     * t2[j];
            s += bf2f((ushort)a1[4 + j]) * t3[j];
        }
        s += __shfl_xor(s, 1); s += __shfl_xor(s, 2); s += __shfl_xor(s, 4);
        if (seg == 0) {
            float o = maskS[r] * disS[r] * (s + ttS[r]) + bias0;
            alphaS[r] = 1.f / (1.f + expf(-o * o));
            atomicAdd(&nuniq, flags[r]);
        }
    }
    __syncthreads();                                           // B3

    {   // ---- k-th largest rank select (8 thr/row, vector gathers) ----
        int nu = nuniq;
        if (nu > 1) {
            float an = alphaS[r];
            int cg = 0, ce = 0;
#pragma unroll
            for (int v = 0; v < 4; ++v) {
                f32x4 A = *(const f32x4*)&alphaS[seg * 16 + 4 * v];
#pragma unroll
                for (int j = 0; j < 4; ++j) { cg += (A[j] > an); ce += (A[j] == an); }
            }
            cg += __shfl_xor(cg, 1); cg += __shfl_xor(cg, 2); cg += __shfl_xor(cg, 4);
            ce += __shfl_xor(ce, 1); ce += __shfl_xor(ce, 2); ce += __shfl_xor(ce, 4);
            if (seg == 0) {
                int idx = (int)ceilf((float)nu * 0.1f);
                if (idx > Nn - 1) idx = Nn - 1;
                if (cg <= idx && idx < cg + ce) cutS = an;  // benign same-value race
            }
        }
    }
    __syncthreads();                                           // B4

    {   // ---- matvec adj*u -> rowc; u inline from alpha/dis ----
        const float cut = cutS;
        short8 a0 = *(const short8*)AP(adjR, r, seg * 16);
        short8 a1 = *(const short8*)AP(adjR, r, seg * 16 + 8);
        float s = 0.f;
#pragma unroll
        for (int v = 0; v < 4; ++v) {
            f32x4 A = *(const f32x4*)&alphaS[seg * 16 + 4 * v];
            f32x4 D = *(const f32x4*)&disS[seg * 16 + 4 * v];
#pragma unroll
            for (int j = 0; j < 4; ++j) {
                float u = fmaxf(A[j] + 1e-7f - cut, 0.f) * D[j];
                float av = (v < 2) ? bf2f((ushort)a0[4 * v + j])
                                   : bf2f((ushort)a1[4 * (v - 2) + j]);
                s += av * u;
            }
        }
        s += __shfl_xor(s, 1); s += __shfl_xor(s, 2); s += __shfl_xor(s, 4);
        if (seg == 0) {
            float ur   = fmaxf(alphaS[r] + 1e-7f - cut, 0.f) * disS[r];
            float rsum = maskS[r] * disS[r] * (ur + s);
            rowcS[r]   = maskS[r] * disS[r] / fmaxf(rsum, 1e-12f);
        }
    }
    __syncthreads();                                           // B5

    // ---- build ST[m][k] = rowc_k*(adj[k][m]+delta)*u_m (bf16, swizzled) ----
    {
        const float cut = cutS;
        const int m = t & 127, sl = t >> 7, k0 = sl * 16;
        const float um = fmaxf(alphaS[m] + 1e-7f - cut, 0.f) * disS[m];
        float vv[16];
#pragma unroll
        for (int j = 0; j < 16; ++j) {
            int k = k0 + j;
            vv[j] = rowcS[k] * (bf2f(*AP(adjR, k, m)) + ((k == m) ? 1.f : 0.f)) * um;
        }
        uint4 p0, p1;
        p0.x = pk2(vv[0],  vv[1]);  p0.y = pk2(vv[2],  vv[3]);
        p0.z = pk2(vv[4],  vv[5]);  p0.w = pk2(vv[6],  vv[7]);
        p1.x = pk2(vv[8],  vv[9]);  p1.y = pk2(vv[10], vv[11]);
        p1.z = pk2(vv[12], vv[13]); p1.w = pk2(vv[14], vv[15]);
        *(uint4*)AP(stR, m, k0)     = p0;
        *(uint4*)AP(stR, m, k0 + 8) = p1;
    }
    __syncthreads();                                           // B6

    f32x4 acc[4];
    // ---- G2: P = adj * S ----
#pragma unroll
    for (int nt = 0; nt < 4; ++nt) acc[nt] = (f32x4){0.f, 0.f, 0.f, 0.f};
#pragma unroll
    for (int k0 = 0; k0 < 128; k0 += 32) {
        short8 a0 = *(const short8*)AP(adjR, mrow + l15, k0 + quad * 8);
#pragma unroll
        for (int nt = 0; nt < 4; ++nt) {
            short8 bf = *(const short8*)AP(stR, nhalf + nt * 16 + l15, k0 + quad * 8);
            acc[nt] = __builtin_amdgcn_mfma_f32_16x16x32_bf16(a0, bf, acc[nt], 0, 0, 0);
        }
    }
    __syncthreads();                                           // B7: adj bf16 dead

    // ---- write P^T (bf16) into adjR region (same swizzle) ----
#pragma unroll
    for (int nt = 0; nt < 4; ++nt) {
        int j    = nhalf + nt * 16 + l15;
        int mcol = mrow + quad * 4;
        uint2 w2;
        w2.x = pk2(acc[nt][0], acc[nt][1]);
        w2.y = pk2(acc[nt][2], acc[nt][3]);
        *(uint2*)AP(adjR, j, mcol) = w2;
    }
    __syncthreads();                                           // B8

    // ---- G3: nadj = S^T P ----
#pragma unroll
    for (int nt = 0; nt < 4; ++nt) acc[nt] = (f32x4){0.f, 0.f, 0.f, 0.f};
#pragma unroll
    for (int k0 = 0; k0 < 128; k0 += 32) {
        short8 a0 = *(const short8*)AP(stR, mrow + l15, k0 + quad * 8);
#pragma unroll
        for (int nt = 0; nt < 4; ++nt) {
            short8 bf = *(const short8*)AP(adjR, nhalf + nt * 16 + l15, k0 + quad * 8);
            acc[nt] = __builtin_amdgcn_mfma_f32_16x16x32_bf16(a0, bf, acc[nt], 0, 0, 0);
        }
    }
#pragma unroll
    for (int nt = 0; nt < 4; ++nt)
#pragma unroll
        for (int rr2 = 0; rr2 < 4; ++rr2) {
            int row = mrow + quad * 4 + rr2;
            int col = nhalf + nt * 16 + l15;
            nadj[((size_t)b * Nn + row) * Nn + col] = acc[nt][rr2];
        }

    // ---- emb = S^T x from xT0/xT1 (no further barriers) ----
    const int dcb = (w >> 3) * 64;
    f32x4 accE[4];
#pragma unroll
    for (int nt = 0; nt < 4; ++nt) accE[nt] = (f32x4){0.f, 0.f, 0.f, 0.f};
#pragma unroll
    for (int ks = 0; ks < 4; ++ks) {
        short8 aE = *(const short8*)AP(stR, mrow + l15, ks * 32 + quad * 8);
#pragma unroll
        for (int nt = 0; nt < 4; ++nt) {
            short8 bf = *(const short8*)XP(xtR0, dcb + nt * 16 + l15, ks * 16 + quad * 4);
            accE[nt] = __builtin_amdgcn_mfma_f32_16x16x32_bf16(aE, bf, accE[nt], 0, 0, 0);
        }
    }
#pragma unroll
    for (int nt = 0; nt < 4; ++nt)
#pragma unroll
        for (int rr2 = 0; rr2 < 4; ++rr2) {
            int row = mrow + quad * 4 + rr2;
            int col = dcb + nt * 16 + l15;
            emb[((size_t)b * Nn + row) * Dd + col] = accE[nt][rr2];
        }

#pragma unroll
    for (int nt = 0; nt < 4; ++nt) accE[nt] = (f32x4){0.f, 0.f, 0.f, 0.f};
#pragma unroll
    for (int ks = 0; ks < 4; ++ks) {
        short8 aE = *(const short8*)AP(stR, mrow + l15, ks * 32 + quad * 8);
#pragma unroll
        for (int nt = 0; nt < 4; ++nt) {
            short8 bf = *(const short8*)XP(xtR1, dcb + nt * 16 + l15, ks * 16 + quad * 4);
            accE[nt] = __builtin_amdgcn_mfma_f32_16x16x32_bf16(aE, bf, accE[nt], 0, 0, 0);
        }
    }
#pragma unroll
    for (int nt = 0; nt < 4; ++nt)
#pragma unroll
        for (int rr2 = 0; rr2 < 4; ++rr2) {
            int row = mrow + quad * 4 + rr2;
            int col = 128 + dcb + nt * 16 + l15;
            emb[((size_t)b * Nn + row) * Dd + col] = accE[nt][rr2];
        }
}

extern "C" void kernel_launch(void* const* d_in, const int* in_sizes, int n_in,
                              void* d_out, int out_size, void* d_ws, size_t ws_size,
                              hipStream_t stream)
{
    const float* x     = (const float*)d_in[0];
    const float* adj   = (const float*)d_in[1];
    const int*   head  = (const int*)d_in[2];
    const float* lin_w = (const float*)d_in[3];
    const float* bias  = (const float*)d_in[4];

    float* emb  = (float*)d_out;                 // [B,N,D]
    float* nadj = emb + (size_t)Bsz * Nn * Dd;   // [B,N,N]

    mega<<<Bsz, 1024, 0, stream>>>(x, adj, head, lin_w, bias, emb, nadj);
}